// Round 3
// baseline (1356.465 us; speedup 1.0000x reference)
//
#include <hip/hip_runtime.h>

// Grouped SwiGLU MLP, MI355X gfx950.
// Round 4: persistent multi-tile blocks, flat pipelined K-stream.
//   grid = 256 blocks (1/CU). Each block: fixed (g, n-panel), sweeps m-tiles
//   (gemm1: 16 tiles, gemm2: 4 tiles) as ONE continuous 8-phase counted-vmcnt
//   stream -- staging never drains at tile boundaries; one prologue per block.
//   Per-tile epilogue (store acc + rezero) runs between p7-barrier and next p0
//   while background staging continues. vmcnt(6) invariants hold across tiles
//   (K-tiles/tile is even -> parity of global K-tile index continues; buffer
//   = (Tg&1)*2+kk rotation is seamless; every read >=7 loads behind newest).
// Phase structure unchanged from Round 3 (opaque asm ds_read_b128, barrier,
// lgkmcnt(0)+sched_barrier, setprio around 16xMFMA, vmcnt(6) at p3/p7 only).

#define GN 8
#define DN 1024
#define HN 2048
#define ON 1024

typedef __attribute__((ext_vector_type(8))) short short8;
typedef __attribute__((ext_vector_type(4))) float f32x4;
typedef __attribute__((ext_vector_type(4))) unsigned int u32x4;

#define BARR() __builtin_amdgcn_s_barrier()
#define WAIT_LGKM0()                                       \
  do {                                                     \
    asm volatile("s_waitcnt lgkmcnt(0)" ::: "memory");     \
    __builtin_amdgcn_sched_barrier(0);                     \
  } while (0)

// ds_read_b128 with compile-time byte offset; opaque to alias analysis.
#define DS128(dst, base, imm)                                                  \
  asm volatile("ds_read_b128 %0, %1 offset:" #imm                              \
               : "=v"(dst)                                                     \
               : "v"((const __attribute__((address_space(3))) unsigned short*)(base)))

__device__ __forceinline__ void async16(const void* g, void* l) {
  __builtin_amdgcn_global_load_lds(
      (const __attribute__((address_space(1))) void*)g,
      (__attribute__((address_space(3))) void*)l, 16, 0, 0);
}

__device__ __forceinline__ unsigned short f2bf(float f) {
  unsigned int u = __float_as_uint(f);
  u += 0x7FFFu + ((u >> 16) & 1u);  // round-to-nearest-even
  return (unsigned short)(u >> 16);
}

__global__ __launch_bounds__(256) void cvt_f32_bf16(
    const float* __restrict__ in, unsigned short* __restrict__ out, int n) {
  int t = blockIdx.x * 256 + threadIdx.x;
  int i = t * 8;
  if (i >= n) return;
  f32x4 a = *(const f32x4*)(in + i);
  f32x4 b = *(const f32x4*)(in + i + 4);
  u32x4 r;
  r.x = (unsigned)f2bf(a.x) | ((unsigned)f2bf(a.y) << 16);
  r.y = (unsigned)f2bf(a.z) | ((unsigned)f2bf(a.w) << 16);
  r.z = (unsigned)f2bf(b.x) | ((unsigned)f2bf(b.y) << 16);
  r.w = (unsigned)f2bf(b.z) | ((unsigned)f2bf(b.w) << 16);
  *(u32x4*)(out + i) = r;
}

// ---------------- Phase 1: gate/up dual GEMM + SwiGLU -> hidden bf16 --------
// 256 blocks: bid = g(3b) | n(4b) | mh(1b). Each block: 16 m-tiles of 256 rows
// at fixed (g, n0=128-col panel). TOTK = 16 tiles * 16 K-tiles = 256.
__global__ __launch_bounds__(512, 2) void gemm1_swiglu(
    const unsigned short* __restrict__ Xb, const unsigned short* __restrict__ Wgb,
    const unsigned short* __restrict__ Wub, unsigned short* __restrict__ Hid) {
  extern __shared__ unsigned short sm[];
  unsigned short* sA = sm;            // 4 bufs x 256x32 (64KB)
  unsigned short* sG = sm + 32768;    // 4 bufs x 128x32 (32KB)
  unsigned short* sU = sm + 49152;    // 4 bufs x 128x32 (32KB)

  const int bid = blockIdx.x;
  const int g = bid >> 5;
  const int n0 = ((bid >> 1) & 15) * 128;
  const int mh = bid & 1;  // m-half: tiles mh*16 .. mh*16+15

  const int tid = threadIdx.x;
  const int lane = tid & 63;
  const int w = tid >> 6;
  const int wm = w >> 2, wn = w & 3;
  const int fr = lane & 15, fc = lane >> 4;
  const int sR = (fc + ((fr >> 1) & 3)) & 3;  // read-side chunk swizzle

  // staging sources (global pre-swizzled so linear LDS write == swizzled tile)
  const unsigned short* aBase[2];  // for tile 0 of this block
  unsigned short* aDst[2];
#pragma unroll
  for (int j = 0; j < 2; ++j) {
    int R = j * 128 + w * 16 + (lane >> 2);
    int c = ((lane & 3) - ((R >> 1) & 3)) & 3;
    aBase[j] = Xb + ((size_t)((mh * 4096 + R) * 8 + g)) * DN + c * 8;
    aDst[j] = &sA[(j * 128 + w * 16) * 32];
  }
  const unsigned short *gSrc, *uSrc;
  unsigned short *gDst, *uDst;
  {
    int R = w * 16 + (lane >> 2);
    int c = ((lane & 3) - ((R >> 1) & 3)) & 3;
    gSrc = Wgb + ((size_t)(g * HN + n0 + R)) * DN + c * 8;
    uSrc = Wub + ((size_t)(g * HN + n0 + R)) * DN + c * 8;
    gDst = &sG[(w * 16) * 32];
    uDst = &sU[(w * 16) * 32];
  }

  auto stageA = [&](int Tg, int kk) {  // 2 loads/thread
    const int buf = (Tg & 1) * 2 + kk;
    const size_t toff = (size_t)(Tg >> 4) * (256u * 8u * DN);
    const int ko = (Tg & 15) * 64 + kk * 32;
#pragma unroll
    for (int j = 0; j < 2; ++j)
      async16(aBase[j] + toff + ko, aDst[j] + buf * 8192);
  };
  auto stageB = [&](int Tg, int kk) {  // 2 loads/thread (Bg + Bu)
    const int buf = (Tg & 1) * 2 + kk;
    const int ko = (Tg & 15) * 64 + kk * 32;  // B K-range repeats per tile
    async16(gSrc + ko, gDst + buf * 4096);
    async16(uSrc + ko, uDst + buf * 4096);
  };
  auto readA = [&](int Tg, int kk, short8* a) {
    const unsigned short* p =
        sA + ((Tg & 1) * 2 + kk) * 8192 + (wm * 128 + fr) * 32 + sR * 8;
    DS128(a[0], p, 0);
    DS128(a[1], p, 1024);
    DS128(a[2], p, 2048);
    DS128(a[3], p, 3072);
    DS128(a[4], p, 4096);
    DS128(a[5], p, 5120);
    DS128(a[6], p, 6144);
    DS128(a[7], p, 7168);
  };
  auto readB = [&](const unsigned short* base, int Tg, int kk, short8* b) {
    const unsigned short* p =
        base + ((Tg & 1) * 2 + kk) * 4096 + (wn * 32 + fr) * 32 + sR * 8;
    DS128(b[0], p, 0);
    DS128(b[1], p, 1024);
  };

  f32x4 accg[8][2], accu[8][2];
#pragma unroll
  for (int mi = 0; mi < 8; ++mi)
#pragma unroll
    for (int ni = 0; ni < 2; ++ni) {
      accg[mi][ni] = (f32x4)(0.0f);
      accu[mi][ni] = (f32x4)(0.0f);
    }

  auto mm16 = [&](const short8* a, const short8* b, f32x4(*acc)[2]) {
    __builtin_amdgcn_s_setprio(1);
#pragma unroll
    for (int mi = 0; mi < 8; ++mi)
#pragma unroll
      for (int ni = 0; ni < 2; ++ni)
        acc[mi][ni] = __builtin_amdgcn_mfma_f32_16x16x32_bf16(
            a[mi], b[ni], acc[mi][ni], 0, 0, 0);
    __builtin_amdgcn_s_setprio(0);
  };

  // prologue (once per block): 7 units; vmcnt(6) => K-tile 0 resident
  stageA(0, 0); stageB(0, 0); stageA(0, 1); stageB(0, 1);
  stageA(1, 0); stageB(1, 0); stageA(1, 1);
  asm volatile("s_waitcnt vmcnt(6)" ::: "memory");
  BARR();

  short8 af[8], bg[2], bu[2];
  const int q = lane >> 4, cl = lane & 15;
  const int NIT = 128;  // 256 K-tiles / 2
#pragma unroll 1
  for (int it = 0; it < NIT; ++it) {
    const int T = 2 * it;
    const bool full = (it + 1 < NIT);
    // ---- p0 ----
    readA(T, 0, af); readB(sG, T, 0, bg);
    stageB(T + 1, 1);
    BARR();
    WAIT_LGKM0();
    mm16(af, bg, accg);
    BARR();
    // ---- p1 ----
    readB(sU, T, 0, bu);
    if (full) stageA(T + 2, 0);
    BARR();
    WAIT_LGKM0();
    mm16(af, bu, accu);
    BARR();
    // ---- p2 ----
    readA(T, 1, af); readB(sG, T, 1, bg);
    if (full) stageB(T + 2, 0);
    BARR();
    WAIT_LGKM0();
    mm16(af, bg, accg);
    BARR();
    // ---- p3 ----
    readB(sU, T, 1, bu);
    if (full) stageA(T + 2, 1);
    BARR();
    WAIT_LGKM0();
    mm16(af, bu, accu);
    if (full) { asm volatile("s_waitcnt vmcnt(6)" ::: "memory"); }
    else      { asm volatile("s_waitcnt vmcnt(0)" ::: "memory"); }
    BARR();
    // ---- p4 ----
    readA(T + 1, 0, af); readB(sG, T + 1, 0, bg);
    if (full) stageB(T + 2, 1);
    BARR();
    WAIT_LGKM0();
    mm16(af, bg, accg);
    BARR();
    // ---- p5 ----
    readB(sU, T + 1, 0, bu);
    if (full) stageA(T + 3, 0);
    BARR();
    WAIT_LGKM0();
    mm16(af, bu, accu);
    BARR();
    // ---- p6 ----
    readA(T + 1, 1, af); readB(sG, T + 1, 1, bg);
    if (full) stageB(T + 3, 0);
    BARR();
    WAIT_LGKM0();
    mm16(af, bg, accg);
    BARR();
    // ---- p7 ----
    readB(sU, T + 1, 1, bu);
    if (full) stageA(T + 3, 1);
    BARR();
    WAIT_LGKM0();
    mm16(af, bu, accu);
    if (full) { asm volatile("s_waitcnt vmcnt(6)" ::: "memory"); }
    BARR();
    // ---- per-tile epilogue (staging continues in background) ----
    if ((T & 15) == 14) {
      const int tile = T >> 4;
      const int m0 = (mh * 16 + tile) * 256;
#pragma unroll
      for (int mi = 0; mi < 8; ++mi)
#pragma unroll
        for (int ni = 0; ni < 2; ++ni) {
          int hcol = n0 + wn * 32 + ni * 16 + cl;
#pragma unroll
          for (int i2 = 0; i2 < 4; ++i2) {
            int b = m0 + wm * 128 + mi * 16 + q * 4 + i2;
            float gf = accg[mi][ni][i2];
            float uf = accu[mi][ni][i2];
            float hv = (gf / (1.0f + __expf(-gf))) * uf;
            Hid[((size_t)(b * 8 + g)) * HN + hcol] = f2bf(hv);
          }
          accg[mi][ni] = (f32x4)(0.0f);
          accu[mi][ni] = (f32x4)(0.0f);
        }
    }
  }
}

// ---------------- Phase 2: hidden @ Wd^T -> out fp32 ------------------------
// 256 blocks: bid = g(3b) | n(2b) | mq(3b). Each block: 4 m-tiles of 256 rows
// at fixed (g, n0=256-col panel). TOTK = 4 tiles * 32 K-tiles = 128.
__global__ __launch_bounds__(512, 2) void gemm2_down(
    const unsigned short* __restrict__ Hid, const unsigned short* __restrict__ Wdb,
    float* __restrict__ Out) {
  extern __shared__ unsigned short sm[];
  unsigned short* sA = sm;            // 4 x 256x32
  unsigned short* sB = sm + 32768;    // 4 x 256x32

  const int bid = blockIdx.x;
  const int g = bid >> 5;
  const int n0 = ((bid >> 3) & 3) * 256;
  const int mq = bid & 7;  // m-quarter: tiles mq*4 .. mq*4+3

  const int tid = threadIdx.x;
  const int lane = tid & 63;
  const int w = tid >> 6;
  const int wm = w >> 2, wn = w & 3;
  const int fr = lane & 15, fc = lane >> 4;
  const int sR = (fc + ((fr >> 1) & 3)) & 3;

  const unsigned short* aBase[2];
  const unsigned short* bSrc[2];
  unsigned short* aDst[2];
  unsigned short* bDst[2];
#pragma unroll
  for (int j = 0; j < 2; ++j) {
    int R = j * 128 + w * 16 + (lane >> 2);
    int c = ((lane & 3) - ((R >> 1) & 3)) & 3;
    aBase[j] = Hid + ((size_t)((mq * 1024 + R) * 8 + g)) * HN + c * 8;
    bSrc[j] = Wdb + ((size_t)(g * ON + n0 + R)) * HN + c * 8;
    aDst[j] = &sA[(j * 128 + w * 16) * 32];
    bDst[j] = &sB[(j * 128 + w * 16) * 32];
  }

  auto stageA = [&](int Tg, int kk) {
    const int buf = (Tg & 1) * 2 + kk;
    const size_t toff = (size_t)(Tg >> 5) * (256u * 8u * HN);
    const int ko = (Tg & 31) * 64 + kk * 32;
#pragma unroll
    for (int j = 0; j < 2; ++j)
      async16(aBase[j] + toff + ko, aDst[j] + buf * 8192);
  };
  auto stageB = [&](int Tg, int kk) {
    const int buf = (Tg & 1) * 2 + kk;
    const int ko = (Tg & 31) * 64 + kk * 32;  // B K-range repeats per tile
#pragma unroll
    for (int j = 0; j < 2; ++j) async16(bSrc[j] + ko, bDst[j] + buf * 8192);
  };
  auto readA = [&](int Tg, int kk, short8* a) {
    const unsigned short* p =
        sA + ((Tg & 1) * 2 + kk) * 8192 + (wm * 128 + fr) * 32 + sR * 8;
    DS128(a[0], p, 0);
    DS128(a[1], p, 1024);
    DS128(a[2], p, 2048);
    DS128(a[3], p, 3072);
    DS128(a[4], p, 4096);
    DS128(a[5], p, 5120);
    DS128(a[6], p, 6144);
    DS128(a[7], p, 7168);
  };
  auto readB = [&](int Tg, int kk, int nb, short8* b) {
    const unsigned short* p =
        sB + ((Tg & 1) * 2 + kk) * 8192 + (wn * 64 + nb * 16 + fr) * 32 + sR * 8;
    DS128(b[0], p, 0);
    DS128(b[1], p, 1024);
  };

  f32x4 acc[8][4];
#pragma unroll
  for (int mi = 0; mi < 8; ++mi)
#pragma unroll
    for (int ni = 0; ni < 4; ++ni) acc[mi][ni] = (f32x4)(0.0f);

  auto mm16 = [&](const short8* a, const short8* b, int nb) {
    __builtin_amdgcn_s_setprio(1);
#pragma unroll
    for (int mi = 0; mi < 8; ++mi)
#pragma unroll
      for (int nj = 0; nj < 2; ++nj)
        acc[mi][nb + nj] = __builtin_amdgcn_mfma_f32_16x16x32_bf16(
            a[mi], b[nj], acc[mi][nb + nj], 0, 0, 0);
    __builtin_amdgcn_s_setprio(0);
  };

  stageA(0, 0); stageB(0, 0); stageA(0, 1); stageB(0, 1);
  stageA(1, 0); stageB(1, 0); stageA(1, 1);
  asm volatile("s_waitcnt vmcnt(6)" ::: "memory");
  BARR();

  short8 af[8], bf[2];
  const int q = lane >> 4, cl = lane & 15;
  const int NIT = 64;  // 128 K-tiles / 2
#pragma unroll 1
  for (int it = 0; it < NIT; ++it) {
    const int T = 2 * it;
    const bool full = (it + 1 < NIT);
    // ---- p0 ----
    readA(T, 0, af); readB(T, 0, 0, bf);
    stageB(T + 1, 1);
    BARR();
    WAIT_LGKM0();
    mm16(af, bf, 0);
    BARR();
    // ---- p1 ----
    readB(T, 0, 2, bf);
    if (full) stageA(T + 2, 0);
    BARR();
    WAIT_LGKM0();
    mm16(af, bf, 2);
    BARR();
    // ---- p2 ----
    readA(T, 1, af); readB(T, 1, 0, bf);
    if (full) stageB(T + 2, 0);
    BARR();
    WAIT_LGKM0();
    mm16(af, bf, 0);
    BARR();
    // ---- p3 ----
    readB(T, 1, 2, bf);
    if (full) stageA(T + 2, 1);
    BARR();
    WAIT_LGKM0();
    mm16(af, bf, 2);
    if (full) { asm volatile("s_waitcnt vmcnt(6)" ::: "memory"); }
    else      { asm volatile("s_waitcnt vmcnt(0)" ::: "memory"); }
    BARR();
    // ---- p4 ----
    readA(T + 1, 0, af); readB(T + 1, 0, 0, bf);
    if (full) stageB(T + 2, 1);
    BARR();
    WAIT_LGKM0();
    mm16(af, bf, 0);
    BARR();
    // ---- p5 ----
    readB(T + 1, 0, 2, bf);
    if (full) stageA(T + 3, 0);
    BARR();
    WAIT_LGKM0();
    mm16(af, bf, 2);
    BARR();
    // ---- p6 ----
    readA(T + 1, 1, af); readB(T + 1, 1, 0, bf);
    if (full) stageB(T + 3, 0);
    BARR();
    WAIT_LGKM0();
    mm16(af, bf, 0);
    BARR();
    // ---- p7 ----
    readB(T + 1, 1, 2, bf);
    if (full) stageA(T + 3, 1);
    BARR();
    WAIT_LGKM0();
    mm16(af, bf, 2);
    if (full) { asm volatile("s_waitcnt vmcnt(6)" ::: "memory"); }
    BARR();
    // ---- per-tile epilogue ----
    if ((T & 31) == 30) {
      const int tile = T >> 5;
      const int m0 = (mq * 4 + tile) * 256;
#pragma unroll
      for (int mi = 0; mi < 8; ++mi)
#pragma unroll
        for (int ni = 0; ni < 4; ++ni) {
          int o = n0 + wn * 64 + ni * 16 + cl;
#pragma unroll
          for (int i2 = 0; i2 < 4; ++i2) {
            int b = m0 + wm * 128 + mi * 16 + q * 4 + i2;
            Out[((size_t)(b * 8 + g)) * ON + o] = acc[mi][ni][i2];
          }
          acc[mi][ni] = (f32x4)(0.0f);
        }
    }
  }
}

extern "C" void kernel_launch(void* const* d_in, const int* in_sizes, int n_in,
                              void* d_out, int out_size, void* d_ws, size_t ws_size,
                              hipStream_t stream) {
  const float* x  = (const float*)d_in[0];   // [65536, 1024]
  const float* Wg = (const float*)d_in[1];   // [8, 2048, 1024]
  const float* Wu = (const float*)d_in[2];   // [8, 2048, 1024]
  const float* Wd = (const float*)d_in[3];   // [8, 1024, 2048]
  float* out = (float*)d_out;                // [65536, 1024]

  const int NX = 65536 * 1024;
  const int NW = GN * HN * DN;

  unsigned short* xb = (unsigned short*)d_ws;
  unsigned short* wg = xb + (size_t)NX;
  unsigned short* wu = wg + (size_t)NW;
  unsigned short* wd = wu + (size_t)NW;
  unsigned short* hid = wd + (size_t)NW;     // [65536, 2048] bf16

  static bool once = false;
  if (!once) {
    hipFuncSetAttribute((const void*)gemm1_swiglu,
                        hipFuncAttributeMaxDynamicSharedMemorySize, 131072);
    hipFuncSetAttribute((const void*)gemm2_down,
                        hipFuncAttributeMaxDynamicSharedMemorySize, 131072);
    once = true;
  }

  cvt_f32_bf16<<<NX / 8 / 256, 256, 0, stream>>>(x, xb, NX);
  cvt_f32_bf16<<<NW / 8 / 256, 256, 0, stream>>>(Wg, wg, NW);
  cvt_f32_bf16<<<NW / 8 / 256, 256, 0, stream>>>(Wu, wu, NW);
  cvt_f32_bf16<<<NW / 8 / 256, 256, 0, stream>>>(Wd, wd, NW);

  gemm1_swiglu<<<dim3(256), dim3(512), 131072, stream>>>(xb, wg, wu, hid);
  gemm2_down<<<dim3(256), dim3(512), 131072, stream>>>(hid, wd, out);
}